// Round 1
// baseline (581.815 us; speedup 1.0000x reference)
//
#include <hip/hip_runtime.h>
#include <hip/hip_bf16.h>

#define GQ 129
#define S_TOTAL (129*129*129)   /* 2146689 spatial points */
#define FDIM 32
#define HID 128
#define DIN 35
#define ROWP 40                 /* padded LDS row stride: 16B-aligned feat block at +4 */

__device__ __forceinline__ float bf_lo(unsigned u) { return __uint_as_float(u << 16); }
__device__ __forceinline__ float bf_hi(unsigned u) { return __uint_as_float(u & 0xffff0000u); }

// ---------------------------------------------------------------------------
// Kernel 1: [C][S] f32  ->  [S][C] bf16 (round-to-nearest-even)
// Reads coalesced along s per channel; each thread writes its 64B row as 4x uint4.
// ---------------------------------------------------------------------------
__global__ __launch_bounds__(256) void transpose_vol(const float* __restrict__ fm,
                                                     unsigned* __restrict__ vol)
{
    int s = blockIdx.x * 256 + threadIdx.x;
    if (s >= S_TOTAL) return;
    unsigned pk[16];
#pragma unroll
    for (int j = 0; j < 16; ++j) {
        float a = fm[(size_t)(2*j)     * S_TOTAL + s];
        float b = fm[(size_t)(2*j + 1) * S_TOTAL + s];
        unsigned ua = __float_as_uint(a); ua = (ua + 0x7fffu + ((ua >> 16) & 1u)) >> 16;
        unsigned ub = __float_as_uint(b); ub = (ub + 0x7fffu + ((ub >> 16) & 1u)) >> 16;
        pk[j] = ua | (ub << 16);
    }
    uint4* o = (uint4*)(vol + (size_t)s * 16);
#pragma unroll
    for (int j = 0; j < 4; ++j)
        o[j] = make_uint4(pk[4*j], pk[4*j+1], pk[4*j+2], pk[4*j+3]);
}

// ---------------------------------------------------------------------------
// Shared MLP epilogue: ex = [px,py,pz, feat[0..31]] -> relu(ex@W1^T+b1)@W2^T+b2
// Weights come from LDS; all lanes read the same address (broadcast, no conflicts).
// ---------------------------------------------------------------------------
__device__ __forceinline__ float mlp_eval(const float* __restrict__ sW1,
                                          const float* __restrict__ sb1,
                                          const float* __restrict__ sW2,
                                          float sb2v,
                                          float px, float py, float pz,
                                          const float feat[FDIM])
{
    float accum = sb2v;
#pragma unroll 4
    for (int h = 0; h < HID; ++h) {
        const float* wr = sW1 + h * ROWP;
        float a = sb1[h];
        a = fmaf(wr[0], px, a);
        a = fmaf(wr[1], py, a);
        a = fmaf(wr[2], pz, a);
        const float4* wf = (const float4*)(wr + 4);
#pragma unroll
        for (int j = 0; j < 8; ++j) {
            float4 w4 = wf[j];
            a = fmaf(w4.x, feat[4*j+0], a);
            a = fmaf(w4.y, feat[4*j+1], a);
            a = fmaf(w4.z, feat[4*j+2], a);
            a = fmaf(w4.w, feat[4*j+3], a);
        }
        accum = fmaf(sW2[h], fmaxf(a, 0.0f), accum);
    }
    return accum;
}

// Stage weights into LDS with the padded/realigned W1 layout.
__device__ __forceinline__ void stage_weights(const float* __restrict__ W1,
                                              const float* __restrict__ b1,
                                              const float* __restrict__ W2,
                                              const float* __restrict__ b2,
                                              float* sW1, float* sb1, float* sW2,
                                              float* sb2v)
{
    int t = threadIdx.x;
    for (int i = t; i < HID * DIN; i += 256) {
        int h = i / DIN, c = i % DIN;
        sW1[h * ROWP + (c < 3 ? c : c + 1)] = W1[i];
    }
    if (t < HID) { sb1[t] = b1[t]; sW2[t] = W2[t]; }
    if (t == 0)  { *sb2v = b2[0]; }
    __syncthreads();
}

// ---------------------------------------------------------------------------
// Kernel 2 (fast path): sample bf16 [S][C] volume + fused MLP.
// ---------------------------------------------------------------------------
__global__ __launch_bounds__(256) void sample_mlp(const float* __restrict__ x,
                                                  const unsigned* __restrict__ vol,
                                                  const float* __restrict__ W1,
                                                  const float* __restrict__ b1,
                                                  const float* __restrict__ W2,
                                                  const float* __restrict__ b2,
                                                  float* __restrict__ out, int npts)
{
    __shared__ float sW1[HID * ROWP];
    __shared__ float sb1[HID];
    __shared__ float sW2[HID];
    __shared__ float sb2v;
    stage_weights(W1, b1, W2, b2, sW1, sb1, sW2, &sb2v);

    int p = blockIdx.x * 256 + threadIdx.x;
    if (p >= npts) return;

    float px = x[3*p + 0], py = x[3*p + 1], pz = x[3*p + 2];
    const float SC = 64.0f / 1.2f;           /* (G-1)/2 / DOMAIN */
    float ix = fmaf(px, SC, 64.0f);
    float iy = fmaf(py, SC, 64.0f);
    float iz = fmaf(pz, SC, 64.0f);
    float fx0 = floorf(ix), fy0 = floorf(iy), fz0 = floorf(iz);
    float fx = ix - fx0, fy = iy - fy0, fz = iz - fz0;
    int ix0 = (int)fx0, iy0 = (int)fy0, iz0 = (int)fz0;
    int x0 = min(max(ix0, 0), GQ-1), x1 = min(max(ix0 + 1, 0), GQ-1);
    int y0 = min(max(iy0, 0), GQ-1), y1 = min(max(iy0 + 1, 0), GQ-1);
    int z0 = min(max(iz0, 0), GQ-1), z1 = min(max(iz0 + 1, 0), GQ-1);

    float feat[FDIM];
#pragma unroll
    for (int c = 0; c < FDIM; ++c) feat[c] = 0.0f;

#pragma unroll
    for (int k = 0; k < 8; ++k) {
        int zi = (k & 4) ? z1 : z0;
        int yi = (k & 2) ? y1 : y0;
        int xi = (k & 1) ? x1 : x0;
        float w = ((k & 4) ? fz : 1.0f - fz)
                * ((k & 2) ? fy : 1.0f - fy)
                * ((k & 1) ? fx : 1.0f - fx);
        const uint4* q = (const uint4*)(vol + (size_t)((zi * GQ + yi) * GQ + xi) * 16);
#pragma unroll
        for (int j = 0; j < 4; ++j) {
            uint4 v = q[j];
            feat[8*j + 0] = fmaf(w, bf_lo(v.x), feat[8*j + 0]);
            feat[8*j + 1] = fmaf(w, bf_hi(v.x), feat[8*j + 1]);
            feat[8*j + 2] = fmaf(w, bf_lo(v.y), feat[8*j + 2]);
            feat[8*j + 3] = fmaf(w, bf_hi(v.y), feat[8*j + 3]);
            feat[8*j + 4] = fmaf(w, bf_lo(v.z), feat[8*j + 4]);
            feat[8*j + 5] = fmaf(w, bf_hi(v.z), feat[8*j + 5]);
            feat[8*j + 6] = fmaf(w, bf_lo(v.w), feat[8*j + 6]);
            feat[8*j + 7] = fmaf(w, bf_hi(v.w), feat[8*j + 7]);
        }
    }

    out[p] = mlp_eval(sW1, sb1, sW2, sb2v, px, py, pz, feat);
}

// ---------------------------------------------------------------------------
// Kernel 2 (fallback): sample original [C][S] f32 layout directly (ws too small).
// ---------------------------------------------------------------------------
__global__ __launch_bounds__(256) void sample_mlp_direct(const float* __restrict__ x,
                                                         const float* __restrict__ fm,
                                                         const float* __restrict__ W1,
                                                         const float* __restrict__ b1,
                                                         const float* __restrict__ W2,
                                                         const float* __restrict__ b2,
                                                         float* __restrict__ out, int npts)
{
    __shared__ float sW1[HID * ROWP];
    __shared__ float sb1[HID];
    __shared__ float sW2[HID];
    __shared__ float sb2v;
    stage_weights(W1, b1, W2, b2, sW1, sb1, sW2, &sb2v);

    int p = blockIdx.x * 256 + threadIdx.x;
    if (p >= npts) return;

    float px = x[3*p + 0], py = x[3*p + 1], pz = x[3*p + 2];
    const float SC = 64.0f / 1.2f;
    float ix = fmaf(px, SC, 64.0f);
    float iy = fmaf(py, SC, 64.0f);
    float iz = fmaf(pz, SC, 64.0f);
    float fx0 = floorf(ix), fy0 = floorf(iy), fz0 = floorf(iz);
    float fx = ix - fx0, fy = iy - fy0, fz = iz - fz0;
    int ix0 = (int)fx0, iy0 = (int)fy0, iz0 = (int)fz0;
    int x0 = min(max(ix0, 0), GQ-1), x1 = min(max(ix0 + 1, 0), GQ-1);
    int y0 = min(max(iy0, 0), GQ-1), y1 = min(max(iy0 + 1, 0), GQ-1);
    int z0 = min(max(iz0, 0), GQ-1), z1 = min(max(iz0 + 1, 0), GQ-1);

    int  sidx[8];
    float cw[8];
#pragma unroll
    for (int k = 0; k < 8; ++k) {
        int zi = (k & 4) ? z1 : z0;
        int yi = (k & 2) ? y1 : y0;
        int xi = (k & 1) ? x1 : x0;
        sidx[k] = (zi * GQ + yi) * GQ + xi;
        cw[k] = ((k & 4) ? fz : 1.0f - fz)
              * ((k & 2) ? fy : 1.0f - fy)
              * ((k & 1) ? fx : 1.0f - fx);
    }

    float feat[FDIM];
#pragma unroll
    for (int c = 0; c < FDIM; ++c) {
        const float* base = fm + (size_t)c * S_TOTAL;
        float a = 0.0f;
#pragma unroll
        for (int k = 0; k < 8; ++k) a = fmaf(cw[k], base[sidx[k]], a);
        feat[c] = a;
    }

    out[p] = mlp_eval(sW1, sb1, sW2, sb2v, px, py, pz, feat);
}

extern "C" void kernel_launch(void* const* d_in, const int* in_sizes, int n_in,
                              void* d_out, int out_size, void* d_ws, size_t ws_size,
                              hipStream_t stream)
{
    const float* x  = (const float*)d_in[0];
    const float* fm = (const float*)d_in[1];
    const float* W1 = (const float*)d_in[2];
    const float* b1 = (const float*)d_in[3];
    const float* W2 = (const float*)d_in[4];
    const float* b2 = (const float*)d_in[5];
    float* out = (float*)d_out;
    int npts = in_sizes[0] / 3;

    size_t need = (size_t)S_TOTAL * FDIM * sizeof(unsigned short); /* bf16 volume */
    if (ws_size >= need) {
        unsigned* vol = (unsigned*)d_ws;
        transpose_vol<<<(S_TOTAL + 255) / 256, 256, 0, stream>>>(fm, vol);
        sample_mlp<<<(npts + 255) / 256, 256, 0, stream>>>(x, vol, W1, b1, W2, b2, out, npts);
    } else {
        sample_mlp_direct<<<(npts + 255) / 256, 256, 0, stream>>>(x, fm, W1, b1, W2, b2, out, npts);
    }
}

// Round 2
// 523.636 us; speedup vs baseline: 1.1111x; 1.1111x over previous
//
#include <hip/hip_runtime.h>
#include <hip/hip_bf16.h>

#define GQ 129
#define S_TOTAL (129*129*129)   /* 2146689 spatial points */
#define FDIM 32
#define HID 128
#define DIN 35
#define ROWP 40                 /* padded LDS row stride for fallback path */

typedef short short8 __attribute__((ext_vector_type(8)));
typedef float f32x4  __attribute__((ext_vector_type(4)));

__device__ __forceinline__ float bf_lo(unsigned u) { return __uint_as_float(u << 16); }
__device__ __forceinline__ float bf_hi(unsigned u) { return __uint_as_float(u & 0xffff0000u); }
__device__ __forceinline__ unsigned short f2bf(float f) {
    unsigned u = __float_as_uint(f);
    return (unsigned short)((u + 0x7fffu + ((u >> 16) & 1u)) >> 16);
}
__device__ __forceinline__ float bf2f(unsigned short h) {
    return __uint_as_float(((unsigned)h) << 16);
}

// ---------------------------------------------------------------------------
// Kernel 1: [C][S] f32  ->  [S][C] bf16 (round-to-nearest-even). Unchanged.
// ---------------------------------------------------------------------------
__global__ __launch_bounds__(256) void transpose_vol(const float* __restrict__ fm,
                                                     unsigned* __restrict__ vol)
{
    int s = blockIdx.x * 256 + threadIdx.x;
    if (s >= S_TOTAL) return;
    unsigned pk[16];
#pragma unroll
    for (int j = 0; j < 16; ++j) {
        float a = fm[(size_t)(2*j)     * S_TOTAL + s];
        float b = fm[(size_t)(2*j + 1) * S_TOTAL + s];
        unsigned ua = __float_as_uint(a); ua = (ua + 0x7fffu + ((ua >> 16) & 1u)) >> 16;
        unsigned ub = __float_as_uint(b); ub = (ub + 0x7fffu + ((ub >> 16) & 1u)) >> 16;
        pk[j] = ua | (ub << 16);
    }
    uint4* o = (uint4*)(vol + (size_t)s * 16);
#pragma unroll
    for (int j = 0; j < 4; ++j)
        o[j] = make_uint4(pk[4*j], pk[4*j+1], pk[4*j+2], pk[4*j+3]);
}

// ---------------------------------------------------------------------------
// Kernel 2 (fast path): per-wave MFMA MLP.
//
// Wave tile: 16 points x 128 hidden, via 8 hid-tiles x 2 K-halves of
// mfma_f32_16x16x32_bf16.  K-slot assignment (our own bijection, used
// consistently for A and B):
//   half0 g=0: [xh0 xh1 xh2 xl0 xl1 xl2 0 0]   . [Wh0 Wh1 Wh2 Wh0 Wh1 Wh2 0 0]
//   half0 g=1: [xh0 xh1 xh2 0 0 0 0 0]         . [Wl0 Wl1 Wl2 0 0 0 0 0]
//   half0 g=2: feat[0..7]                      . Wf[0..7]
//   half0 g=3: feat[8..15]                     . Wf[8..15]
//   half1 g=0: feat[16..23]                    . Wf[16..23]
//   half1 g=1: feat[24..31]                    . Wf[24..31]
//   half1 g=2,3: zeros                         . zeros
// => layer1 = xh.Wh + xl.Wh + xh.Wl (f32-accurate x part) + bf16 feat part.
// C/D: col = lane&15 (hid), row = (lane>>4)*4 + reg (point)  [m89-verified].
// ---------------------------------------------------------------------------
__global__ __launch_bounds__(256) void sample_mlp_mfma(const float* __restrict__ x,
                                                       const unsigned* __restrict__ vol,
                                                       const float* __restrict__ W1,
                                                       const float* __restrict__ b1,
                                                       const float* __restrict__ W2,
                                                       const float* __restrict__ b2,
                                                       float* __restrict__ out, int npts)
{
    const int lane = threadIdx.x & 63;
    const int wave = blockIdx.x * 4 + (threadIdx.x >> 6);
    const int nwaves = gridDim.x * 4;
    const int c = lane & 15;      // A: point row within tile; B: hid col within tile
    const int g = lane >> 4;      // k-slot group

    // ---- one-time per-wave: B fragments + per-lane b1/W2 slices ----
    short8 B0[8], B1[8];
    float b1v[8], w2v[8];
#pragma unroll
    for (int t = 0; t < 8; ++t) {
        const float* wr = W1 + (t*16 + c) * DIN;
        short8 f0 = (short8)0, f1 = (short8)0;
        if (g == 0) {
            short h0 = (short)f2bf(wr[0]), h1 = (short)f2bf(wr[1]), h2 = (short)f2bf(wr[2]);
            f0[0] = h0; f0[1] = h1; f0[2] = h2; f0[3] = h0; f0[4] = h1; f0[5] = h2;
#pragma unroll
            for (int j = 0; j < 8; ++j) f1[j] = (short)f2bf(wr[3 + 16 + j]);
        } else if (g == 1) {
#pragma unroll
            for (int d = 0; d < 3; ++d) {
                unsigned short hh = f2bf(wr[d]);
                f0[d] = (short)f2bf(wr[d] - bf2f(hh));
            }
#pragma unroll
            for (int j = 0; j < 8; ++j) f1[j] = (short)f2bf(wr[3 + 24 + j]);
        } else if (g == 2) {
#pragma unroll
            for (int j = 0; j < 8; ++j) f0[j] = (short)f2bf(wr[3 + j]);
        } else {
#pragma unroll
            for (int j = 0; j < 8; ++j) f0[j] = (short)f2bf(wr[3 + 8 + j]);
        }
        B0[t] = f0; B1[t] = f1;
        b1v[t] = b1[t*16 + c];
        w2v[t] = W2[t*16 + c];
    }
    const float b2v = b2[0];

    // this lane's feature-channel block (g=0:16..23, g=1:24..31, g=2:0..7, g=3:8..15)
    const int cb = ((g + 2) & 3) * 8;
    const char* volb = (const char*)vol + cb * 2;

    const int ntiles = (npts + 15) >> 4;
    for (int tile = wave; tile < ntiles; tile += nwaves) {
        const int p0 = tile << 4;
        const int p  = p0 + c;
        const int pc = min(p, npts - 1);
        float px = x[3*pc], py = x[3*pc + 1], pz = x[3*pc + 2];
        const float SC = 64.0f / 1.2f;
        float ix = fmaf(px, SC, 64.0f), iy = fmaf(py, SC, 64.0f), iz = fmaf(pz, SC, 64.0f);
        float fx0 = floorf(ix), fy0 = floorf(iy), fz0 = floorf(iz);
        float fx = ix - fx0, fy = iy - fy0, fz = iz - fz0;
        int ix0 = (int)fx0, iy0 = (int)fy0, iz0 = (int)fz0;
        int x0 = min(max(ix0, 0), GQ-1), x1 = min(max(ix0 + 1, 0), GQ-1);
        int y0 = min(max(iy0, 0), GQ-1), y1 = min(max(iy0 + 1, 0), GQ-1);
        int z0 = min(max(iz0, 0), GQ-1), z1 = min(max(iz0 + 1, 0), GQ-1);

        // issue all 8 gathers first, then interpolate
        uint4 cv[8]; float w8[8];
#pragma unroll
        for (int k = 0; k < 8; ++k) {
            int zi = (k & 4) ? z1 : z0;
            int yi = (k & 2) ? y1 : y0;
            int xi = (k & 1) ? x1 : x0;
            w8[k] = ((k & 4) ? fz : 1.0f - fz)
                  * ((k & 2) ? fy : 1.0f - fy)
                  * ((k & 1) ? fx : 1.0f - fx);
            cv[k] = *(const uint4*)(volb + (size_t)((zi*GQ + yi)*GQ + xi) * 64);
        }
        float F[8];
#pragma unroll
        for (int j = 0; j < 8; ++j) F[j] = 0.0f;
#pragma unroll
        for (int k = 0; k < 8; ++k) {
            float w = w8[k]; uint4 v = cv[k];
            F[0] = fmaf(w, bf_lo(v.x), F[0]); F[1] = fmaf(w, bf_hi(v.x), F[1]);
            F[2] = fmaf(w, bf_lo(v.y), F[2]); F[3] = fmaf(w, bf_hi(v.y), F[3]);
            F[4] = fmaf(w, bf_lo(v.z), F[4]); F[5] = fmaf(w, bf_hi(v.z), F[5]);
            F[6] = fmaf(w, bf_lo(v.w), F[6]); F[7] = fmaf(w, bf_hi(v.w), F[7]);
        }
        short8 Fp;
#pragma unroll
        for (int j = 0; j < 8; ++j) Fp[j] = (short)f2bf(F[j]);

        short8 A0, A1;
        if (g < 2) {
            unsigned short xh0 = f2bf(px), xh1 = f2bf(py), xh2 = f2bf(pz);
            A0 = (short8)0;
            A0[0] = (short)xh0; A0[1] = (short)xh1; A0[2] = (short)xh2;
            if (g == 0) {
                A0[3] = (short)f2bf(px - bf2f(xh0));
                A0[4] = (short)f2bf(py - bf2f(xh1));
                A0[5] = (short)f2bf(pz - bf2f(xh2));
            }
            A1 = Fp;
        } else {
            A0 = Fp;
            A1 = (short8)0;
        }

        f32x4 acc[8];
#pragma unroll
        for (int t = 0; t < 8; ++t) { f32x4 z = {0.f, 0.f, 0.f, 0.f}; acc[t] = z; }
#pragma unroll
        for (int t = 0; t < 8; ++t) {
            acc[t] = __builtin_amdgcn_mfma_f32_16x16x32_bf16(A0, B0[t], acc[t], 0, 0, 0);
            acc[t] = __builtin_amdgcn_mfma_f32_16x16x32_bf16(A1, B1[t], acc[t], 0, 0, 0);
        }

        // layer 2: per-lane partial over its 8 hid channels, then 16-lane butterfly
        float s0 = 0.f, s1 = 0.f, s2 = 0.f, s3 = 0.f;
#pragma unroll
        for (int t = 0; t < 8; ++t) {
            float w2 = w2v[t], bb = b1v[t];
            s0 = fmaf(w2, fmaxf(acc[t][0] + bb, 0.0f), s0);
            s1 = fmaf(w2, fmaxf(acc[t][1] + bb, 0.0f), s1);
            s2 = fmaf(w2, fmaxf(acc[t][2] + bb, 0.0f), s2);
            s3 = fmaf(w2, fmaxf(acc[t][3] + bb, 0.0f), s3);
        }
#pragma unroll
        for (int m = 1; m < 16; m <<= 1) {
            s0 += __shfl_xor(s0, m, 64);
            s1 += __shfl_xor(s1, m, 64);
            s2 += __shfl_xor(s2, m, 64);
            s3 += __shfl_xor(s3, m, 64);
        }
        if (c < 4) {
            int pw = p0 + g*4 + c;
            if (pw < npts) {
                float sv = (c == 0) ? s0 : (c == 1) ? s1 : (c == 2) ? s2 : s3;
                out[pw] = sv + b2v;
            }
        }
    }
}

// ---------------------------------------------------------------------------
// Fallback path (ws too small): previous scalar kernel, unchanged.
// ---------------------------------------------------------------------------
__device__ __forceinline__ float mlp_eval(const float* __restrict__ sW1,
                                          const float* __restrict__ sb1,
                                          const float* __restrict__ sW2,
                                          float sb2v,
                                          float px, float py, float pz,
                                          const float feat[FDIM])
{
    float accum = sb2v;
#pragma unroll 4
    for (int h = 0; h < HID; ++h) {
        const float* wr = sW1 + h * ROWP;
        float a = sb1[h];
        a = fmaf(wr[0], px, a);
        a = fmaf(wr[1], py, a);
        a = fmaf(wr[2], pz, a);
        const float4* wf = (const float4*)(wr + 4);
#pragma unroll
        for (int j = 0; j < 8; ++j) {
            float4 w4 = wf[j];
            a = fmaf(w4.x, feat[4*j+0], a);
            a = fmaf(w4.y, feat[4*j+1], a);
            a = fmaf(w4.z, feat[4*j+2], a);
            a = fmaf(w4.w, feat[4*j+3], a);
        }
        accum = fmaf(sW2[h], fmaxf(a, 0.0f), accum);
    }
    return accum;
}

__device__ __forceinline__ void stage_weights(const float* __restrict__ W1,
                                              const float* __restrict__ b1,
                                              const float* __restrict__ W2,
                                              const float* __restrict__ b2,
                                              float* sW1, float* sb1, float* sW2,
                                              float* sb2v)
{
    int t = threadIdx.x;
    for (int i = t; i < HID * DIN; i += 256) {
        int h = i / DIN, cc = i % DIN;
        sW1[h * ROWP + (cc < 3 ? cc : cc + 1)] = W1[i];
    }
    if (t < HID) { sb1[t] = b1[t]; sW2[t] = W2[t]; }
    if (t == 0)  { *sb2v = b2[0]; }
    __syncthreads();
}

__global__ __launch_bounds__(256) void sample_mlp_direct(const float* __restrict__ x,
                                                         const float* __restrict__ fm,
                                                         const float* __restrict__ W1,
                                                         const float* __restrict__ b1,
                                                         const float* __restrict__ W2,
                                                         const float* __restrict__ b2,
                                                         float* __restrict__ out, int npts)
{
    __shared__ float sW1[HID * ROWP];
    __shared__ float sb1[HID];
    __shared__ float sW2[HID];
    __shared__ float sb2v;
    stage_weights(W1, b1, W2, b2, sW1, sb1, sW2, &sb2v);

    int p = blockIdx.x * 256 + threadIdx.x;
    if (p >= npts) return;

    float px = x[3*p + 0], py = x[3*p + 1], pz = x[3*p + 2];
    const float SC = 64.0f / 1.2f;
    float ix = fmaf(px, SC, 64.0f);
    float iy = fmaf(py, SC, 64.0f);
    float iz = fmaf(pz, SC, 64.0f);
    float fx0 = floorf(ix), fy0 = floorf(iy), fz0 = floorf(iz);
    float fx = ix - fx0, fy = iy - fy0, fz = iz - fz0;
    int ix0 = (int)fx0, iy0 = (int)fy0, iz0 = (int)fz0;
    int x0 = min(max(ix0, 0), GQ-1), x1 = min(max(ix0 + 1, 0), GQ-1);
    int y0 = min(max(iy0, 0), GQ-1), y1 = min(max(iy0 + 1, 0), GQ-1);
    int z0 = min(max(iz0, 0), GQ-1), z1 = min(max(iz0 + 1, 0), GQ-1);

    int  sidx[8];
    float cw[8];
#pragma unroll
    for (int k = 0; k < 8; ++k) {
        int zi = (k & 4) ? z1 : z0;
        int yi = (k & 2) ? y1 : y0;
        int xi = (k & 1) ? x1 : x0;
        sidx[k] = (zi * GQ + yi) * GQ + xi;
        cw[k] = ((k & 4) ? fz : 1.0f - fz)
              * ((k & 2) ? fy : 1.0f - fy)
              * ((k & 1) ? fx : 1.0f - fx);
    }

    float feat[FDIM];
#pragma unroll
    for (int cc = 0; cc < FDIM; ++cc) {
        const float* base = fm + (size_t)cc * S_TOTAL;
        float a = 0.0f;
#pragma unroll
        for (int k = 0; k < 8; ++k) a = fmaf(cw[k], base[sidx[k]], a);
        feat[cc] = a;
    }

    out[p] = mlp_eval(sW1, sb1, sW2, sb2v, px, py, pz, feat);
}

extern "C" void kernel_launch(void* const* d_in, const int* in_sizes, int n_in,
                              void* d_out, int out_size, void* d_ws, size_t ws_size,
                              hipStream_t stream)
{
    const float* x  = (const float*)d_in[0];
    const float* fm = (const float*)d_in[1];
    const float* W1 = (const float*)d_in[2];
    const float* b1 = (const float*)d_in[3];
    const float* W2 = (const float*)d_in[4];
    const float* b2 = (const float*)d_in[5];
    float* out = (float*)d_out;
    int npts = in_sizes[0] / 3;

    size_t need = (size_t)S_TOTAL * FDIM * sizeof(unsigned short); /* bf16 volume */
    if (ws_size >= need) {
        unsigned* vol = (unsigned*)d_ws;
        transpose_vol<<<(S_TOTAL + 255) / 256, 256, 0, stream>>>(fm, vol);
        sample_mlp_mfma<<<512, 256, 0, stream>>>(x, vol, W1, b1, W2, b2, out, npts);
    } else {
        sample_mlp_direct<<<(npts + 255) / 256, 256, 0, stream>>>(x, fm, W1, b1, W2, b2, out, npts);
    }
}